// Round 9
// baseline (1301.704 us; speedup 1.0000x reference)
//
#include <hip/hip_runtime.h>
#include <cstdint>
#include <cstddef>

#define B_DIM 16
#define N_DIM 2048
#define BN (B_DIM * N_DIM)          // 32768 rows per modality
#define QSCALE 0.18033688f          // 0.125 * log2(e): P = exp2(S')
#define PLANE ((size_t)BN * 64)     // elems per partial plane
#define MBPLANE ((size_t)N_DIM * 64) // elems per (modality,batch) tensor block
#define WFRAG_K_OFF (3 * 8 * 64 * 8) // shorts: K-frag area offset in wfrag
#define WFRAG_SHORTS (2 * WFRAG_K_OFF)

typedef __attribute__((ext_vector_type(4))) float f32x4;
typedef __attribute__((ext_vector_type(2))) float f32x2;
typedef __attribute__((ext_vector_type(16))) float f32x16;
typedef __attribute__((ext_vector_type(8))) __bf16 bf16x8;
typedef __attribute__((ext_vector_type(2))) unsigned int u32x2;

__device__ __forceinline__ unsigned short f2bf_rne(float f) {
    union { float f; unsigned int u; } v; v.f = f;
    unsigned int u = v.u;
    return (unsigned short)((u + 0x7fffu + ((u >> 16) & 1u)) >> 16);
}
__device__ __forceinline__ unsigned pk_rne(float a, float b) {
    return (unsigned)f2bf_rne(a) | ((unsigned)f2bf_rne(b) << 16);
}
// half_swap(a,b): res.x = {a.lo32, b.lo32}, res.y = {a.hi32, b.hi32}
__device__ __forceinline__ u32x2 half_swap(unsigned a, unsigned b) {
#if __has_builtin(__builtin_amdgcn_permlane32_swap)
    return __builtin_amdgcn_permlane32_swap(a, b, false, false);
#else
    unsigned pa = (unsigned)__shfl_xor((int)a, 32);
    unsigned pb = (unsigned)__shfl_xor((int)b, 32);
    bool hi = (threadIdx.x & 32) != 0;
    u32x2 r;
    r.x = hi ? pb : a;
    r.y = hi ? b : pa;
    return r;
#endif
}

// ---------------------------------------------------------------------------
// wprep: per-lane W fragments (wq scaled, wk) computed ONCE per modality.
// ---------------------------------------------------------------------------
__global__ __launch_bounds__(64) void wprep_kernel(
    const float* __restrict__ w0, const float* __restrict__ w1, const float* __restrict__ w2,
    unsigned short* __restrict__ wfrag)
{
    int m = blockIdx.x;
    const float* W = (m == 0) ? w0 : (m == 1) ? w1 : w2;
    int lane = threadIdx.x;
    int lq = lane & 31, h = lane >> 5;

    #pragma unroll
    for (int mf = 0; mf < 2; ++mf)
        #pragma unroll
        for (int kc = 0; kc < 4; ++kc) {
            int e  = mf * 32 + lq;
            int d0 = kc * 16 + h * 8;
            unsigned uq[4], uk[4];
            #pragma unroll
            for (int t = 0; t < 4; ++t) {
                int d = d0 + 2 * t;
                uq[t] = pk_rne(W[d * 64 + e] * QSCALE, W[(d + 1) * 64 + e] * QSCALE);
                uk[t] = pk_rne(W[e * 64 + d], W[e * 64 + d + 1]);
            }
            unsigned short* dq = wfrag + ((size_t)((m * 8 + kc * 2 + mf) * 64 + lane)) * 8;
            uint4 a; a.x = uq[0]; a.y = uq[1]; a.z = uq[2]; a.w = uq[3];
            uint4 b; b.x = uk[0]; b.y = uk[1]; b.z = uk[2]; b.w = uk[3];
            *(uint4*)dq = a;
            *(uint4*)(dq + WFRAG_K_OFF) = b;
        }
}

// ---------------------------------------------------------------------------
// prep (MFMA): Q = (x@W)*QSCALE, K = x@W^T, V = x^T — tiled slab layouts:
//   Q: [m][b][g=q/64][qi][chunk 0..7][lq][8elem]
//   K: [m][b][kt=key/64][chunk 0..7][key&63][8elem]   (kt stride 4096 shorts)
//   V: [m][b][kt][keygrp 0..7][d 0..63][8 keys]       (kt stride 4096 shorts)
// ---------------------------------------------------------------------------
__global__ __launch_bounds__(256) void prep_kernel(
    const float* __restrict__ x0, const float* __restrict__ x1, const float* __restrict__ x2,
    const unsigned short* __restrict__ wfrag,
    unsigned short* __restrict__ Qbf, unsigned short* __restrict__ Kbf,
    unsigned short* __restrict__ Vt)
{
    __shared__ float xs[128 * 68];

    int m    = blockIdx.x >> 8;
    int tile = blockIdx.x & 255;
    int row0 = tile * 128;
    int b    = row0 >> 11;
    int n0   = row0 & 2047;
    const float* x = (m == 0) ? x0 : (m == 1) ? x1 : x2;
    int tid = threadIdx.x;

    #pragma unroll
    for (int v = 0; v < 8; ++v) {
        int i4 = v * 256 + tid;
        int r = i4 >> 4, c = (i4 & 15) * 4;
        *(f32x4*)&xs[r * 68 + c] = *(const f32x4*)&x[(size_t)row0 * 64 + i4 * 4];
    }
    __syncthreads();

    int lane = tid & 63, wave = tid >> 6, lq = lane & 31, h = lane >> 5;

    bf16x8 wq[2][4], wk[2][4];
    #pragma unroll
    for (int mf = 0; mf < 2; ++mf)
        #pragma unroll
        for (int kc = 0; kc < 4; ++kc) {
            const unsigned short* fq = wfrag + ((size_t)((m * 8 + kc * 2 + mf) * 64 + lane)) * 8;
            wq[mf][kc] = __builtin_bit_cast(bf16x8, *(const uint4*)fq);
            wk[mf][kc] = __builtin_bit_cast(bf16x8, *(const uint4*)(fq + WFRAG_K_OFF));
        }

    bf16x8 xb[4];
    #pragma unroll
    for (int kc = 0; kc < 4; ++kc) {
        const float* xr = &xs[(wave * 32 + lq) * 68 + kc * 16 + h * 8];
        unsigned u[4];
        #pragma unroll
        for (int t = 0; t < 4; ++t) u[t] = pk_rne(xr[2 * t], xr[2 * t + 1]);
        uint4 ua; ua.x = u[0]; ua.y = u[1]; ua.z = u[2]; ua.w = u[3];
        xb[kc] = __builtin_bit_cast(bf16x8, ua);
    }

    f32x16 Qt[2], Kt[2];
    #pragma unroll
    for (int r = 0; r < 16; ++r) { Qt[0][r] = 0.f; Qt[1][r] = 0.f; Kt[0][r] = 0.f; Kt[1][r] = 0.f; }
    #pragma unroll
    for (int kc = 0; kc < 4; ++kc) {
        #pragma unroll
        for (int mf = 0; mf < 2; ++mf) {
            Qt[mf] = __builtin_amdgcn_mfma_f32_32x32x16_bf16(wq[mf][kc], xb[kc], Qt[mf], 0, 0, 0);
            Kt[mf] = __builtin_amdgcn_mfma_f32_32x32x16_bf16(wk[mf][kc], xb[kc], Kt[mf], 0, 0, 0);
        }
    }

    size_t mbBase = ((size_t)m * B_DIM + b) * MBPLANE;
    int nn  = n0 + wave * 32 + lq;
    int g   = nn >> 6;
    int qi  = (nn >> 5) & 1;
    int ktp = nn >> 6, keyp = nn & 63;
    unsigned short* qb = Qbf + mbBase + (size_t)(g * 2 + qi) * 2048 + lq * 8;
    unsigned short* kb = Kbf + mbBase + (size_t)ktp * 4096 + keyp * 8;

    #pragma unroll
    for (int s = 0; s < 4; ++s) {
        int c = 4 * h + s;
        unsigned q00 = pk_rne(Qt[0][4 * s], Qt[0][4 * s + 1]);
        unsigned q01 = pk_rne(Qt[0][4 * s + 2], Qt[0][4 * s + 3]);
        unsigned q10 = pk_rne(Qt[1][4 * s], Qt[1][4 * s + 1]);
        unsigned q11 = pk_rne(Qt[1][4 * s + 2], Qt[1][4 * s + 3]);
        u32x2 a = half_swap(q00, q10);
        u32x2 cc = half_swap(q01, q11);
        uint4 w; w.x = a.x; w.y = cc.x; w.z = a.y; w.w = cc.y;
        *(uint4*)&qb[c * 256] = w;

        unsigned k00 = pk_rne(Kt[0][4 * s], Kt[0][4 * s + 1]);
        unsigned k01 = pk_rne(Kt[0][4 * s + 2], Kt[0][4 * s + 3]);
        unsigned k10 = pk_rne(Kt[1][4 * s], Kt[1][4 * s + 1]);
        unsigned k11 = pk_rne(Kt[1][4 * s + 2], Kt[1][4 * s + 3]);
        u32x2 a2 = half_swap(k00, k10);
        u32x2 c2 = half_swap(k01, k11);
        uint4 w2; w2.x = a2.x; w2.y = c2.x; w2.z = a2.y; w2.w = c2.y;
        *(uint4*)&kb[c * 512] = w2;
    }

    int d  = tid & 63;
    int ng = tid >> 6;
    #pragma unroll
    for (int s = 0; s < 4; ++s) {
        int keystart = n0 + ng * 32 + 8 * s;
        int ktv = keystart >> 6;
        int cv  = (keystart & 63) >> 3;
        uint4 w;
        int rb = ng * 32 + 8 * s;
        w.x = pk_rne(xs[(rb + 0) * 68 + d], xs[(rb + 1) * 68 + d]);
        w.y = pk_rne(xs[(rb + 2) * 68 + d], xs[(rb + 3) * 68 + d]);
        w.z = pk_rne(xs[(rb + 4) * 68 + d], xs[(rb + 5) * 68 + d]);
        w.w = pk_rne(xs[(rb + 6) * 68 + d], xs[(rb + 7) * 68 + d]);
        *(uint4*)&Vt[mbBase + (size_t)(ktv * 8 + cv) * 512 + d * 8] = w;
    }
}

// ---------------------------------------------------------------------------
// attention R9: NO LDS, NO BARRIERS. K/V fragments are read directly from
// global — after the XCD swizzle the (pair,b) panels are L2-resident
// (R7: FETCH 27 MB), and the fragment reads are 16B/lane fully coalesced,
// so LDS staging was pure overhead (learn_hip common-mistake #7) and its
// 32 KB + per-tile barrier convoy were what capped residency. With the
// 2-way key split (HALVES=2, grid 1536) waves are now limited only by
// VGPR: (256,5) budget 102 >> measured 84 -> 5-6 waves/SIMD, ~2x R7.
// HALVES=2 stores unnormalized O + per-row lsum; reduce combines.
// ---------------------------------------------------------------------------
template<int HALVES>
__global__ __launch_bounds__(256, 5) void attn_kernel(
    const unsigned short* __restrict__ Qbf,
    const unsigned short* __restrict__ Kbf,
    const unsigned short* __restrict__ Vt,
    unsigned short* __restrict__ part,
    float* __restrict__ lsumArr)
{
    constexpr int NT = 32 / HALVES;          // key-tiles per block

    int bid = blockIdx.x;
    int cx  = bid & 7;
    int qt, kh, gh;
    if (HALVES == 2) {                       // 1536 = 8cx * (8qt*2kh) * 12gh
        int r = bid >> 3;
        int t = r & 15;
        gh = r >> 4;
        qt = t & 7;
        kh = t >> 3;
    } else {                                 // 768 = 8cx * 8qt * 12gh
        qt = (bid >> 3) & 7;
        gh = bid >> 6;
        kh = 0;
    }
    int G = gh * 8 + cx;                     // [0,96) = p*16 + b
    int p = G >> 4, b = G & 15;
    int i = p >> 1, jj = p & 1;
    int j = i + 1 + jj; if (j >= 3) j -= 3;
    int kt0 = kh * NT;

    int tid = threadIdx.x, wave = tid >> 6, lane = tid & 63;
    int lq = lane & 31, h = lane >> 5;

    const unsigned short* KgT = Kbf + ((size_t)j * B_DIM + b) * MBPLANE + (size_t)kt0 * 4096;
    const unsigned short* VgT = Vt  + ((size_t)j * B_DIM + b) * MBPLANE + (size_t)kt0 * 4096;
    const unsigned short* QgT = Qbf + ((size_t)i * B_DIM + b) * MBPLANE;

    // Q B-frags: wave owns 64 queries (q = qt*256 + wave*64 + qi*32 + lq)
    int g0 = qt * 4 + wave;
    bf16x8 qf[2][4];
    #pragma unroll
    for (int qi = 0; qi < 2; ++qi)
        #pragma unroll
        for (int kc = 0; kc < 4; ++kc)
            qf[qi][kc] = __builtin_bit_cast(bf16x8, *(const uint4*)&QgT[
                (size_t)(g0 * 2 + qi) * 2048 + (kc * 2 + h) * 256 + lq * 8]);

    f32x16 ZERO;
    #pragma unroll
    for (int r = 0; r < 16; ++r) ZERO[r] = 0.f;

    f32x16 O[2][2];                          // [df][qi]
    #pragma unroll
    for (int r = 0; r < 16; ++r) { O[0][0][r] = 0.f; O[0][1][r] = 0.f; O[1][0][r] = 0.f; O[1][1][r] = 0.f; }
    f32x2 ls2[2]; ls2[0] = (f32x2)(0.f); ls2[1] = (f32x2)(0.f);

    // QK of one 32-key half-stage; K fragments straight from L2 (coalesced 1KB/instr)
    auto QK = [&](const unsigned short* Kb, int kf, f32x16 stv[2]) {
        bf16x8 kfr[4];
        #pragma unroll
        for (int kc = 0; kc < 4; ++kc)
            kfr[kc] = __builtin_bit_cast(bf16x8,
                *(const uint4*)&Kb[(2 * kc + h) * 512 + (kf * 32 + lq) * 8]);
        stv[0] = __builtin_amdgcn_mfma_f32_32x32x16_bf16(kfr[0], qf[0][0], ZERO, 0, 0, 0);
        stv[1] = __builtin_amdgcn_mfma_f32_32x32x16_bf16(kfr[0], qf[1][0], ZERO, 0, 0, 0);
        #pragma unroll
        for (int kc = 1; kc < 4; ++kc) {
            stv[0] = __builtin_amdgcn_mfma_f32_32x32x16_bf16(kfr[kc], qf[0][kc], stv[0], 0, 0, 0);
            stv[1] = __builtin_amdgcn_mfma_f32_32x32x16_bf16(kfr[kc], qf[1][kc], stv[1], 0, 0, 0);
        }
    };

    auto EXPP = [&](const f32x16 stv[2], bf16x8 pf[2][2]) {
        #pragma unroll
        for (int qi = 0; qi < 2; ++qi) {
            unsigned pkk[4][2];
            #pragma unroll
            for (int s = 0; s < 4; ++s) {
                float e0 = __builtin_amdgcn_exp2f(stv[qi][4 * s + 0]);
                float e1 = __builtin_amdgcn_exp2f(stv[qi][4 * s + 1]);
                float e2 = __builtin_amdgcn_exp2f(stv[qi][4 * s + 2]);
                float e3 = __builtin_amdgcn_exp2f(stv[qi][4 * s + 3]);
                f32x2 p01; p01.x = e0; p01.y = e1;
                f32x2 p23; p23.x = e2; p23.y = e3;
                ls2[qi] += p01;              // v_pk_add_f32
                ls2[qi] += p23;
                pkk[s][0] = __builtin_amdgcn_perm(
                    __builtin_bit_cast(unsigned, e1), __builtin_bit_cast(unsigned, e0), 0x07060302u);
                pkk[s][1] = __builtin_amdgcn_perm(
                    __builtin_bit_cast(unsigned, e3), __builtin_bit_cast(unsigned, e2), 0x07060302u);
            }
            #pragma unroll
            for (int c = 0; c < 2; ++c) {
                u32x2 rr0 = half_swap(pkk[2 * c][0], pkk[2 * c + 1][0]);
                u32x2 rr1 = half_swap(pkk[2 * c][1], pkk[2 * c + 1][1]);
                uint4 t; t.x = rr0.x; t.y = rr1.x; t.z = rr0.y; t.w = rr1.y;
                pf[qi][c] = __builtin_bit_cast(bf16x8, t);
            }
        }
    };

    // PV of one half-stage; V fragments straight from L2
    auto PV = [&](const bf16x8 pf[2][2], const unsigned short* Vb, int kfp) {
        #pragma unroll
        for (int c = 0; c < 2; ++c) {
            int kcpv = 2 * kfp + c;
            bf16x8 vfr0 = __builtin_bit_cast(bf16x8,
                *(const uint4*)&Vb[(2 * kcpv + h) * 512 + lq * 8]);
            bf16x8 vfr1 = __builtin_bit_cast(bf16x8,
                *(const uint4*)&Vb[(2 * kcpv + h) * 512 + (32 + lq) * 8]);
            O[0][0] = __builtin_amdgcn_mfma_f32_32x32x16_bf16(vfr0, pf[0][c], O[0][0], 0, 0, 0);
            O[0][1] = __builtin_amdgcn_mfma_f32_32x32x16_bf16(vfr0, pf[1][c], O[0][1], 0, 0, 0);
            O[1][0] = __builtin_amdgcn_mfma_f32_32x32x16_bf16(vfr1, pf[0][c], O[1][0], 0, 0, 0);
            O[1][1] = __builtin_amdgcn_mfma_f32_32x32x16_bf16(vfr1, pf[1][c], O[1][1], 0, 0, 0);
        }
    };

    // pipelined loop (no barriers): exp/PV of previous half-stage between QKs
    f32x16 st[2];
    QK(KgT, 0, st);
    {
        bf16x8 pfA[2][2];
        EXPP(st, pfA);
        QK(KgT, 1, st);
        PV(pfA, VgT, 0);
    }

    for (int lt = 1; lt < NT; ++lt) {
        const unsigned short* Kb = KgT + (size_t)lt * 4096;
        const unsigned short* Vb = VgT + (size_t)lt * 4096;
        {
            bf16x8 pfB[2][2];
            EXPP(st, pfB);
            PV(pfB, Vb - 4096, 1);           // finish tile lt-1
        }
        QK(Kb, 0, st);
        {
            bf16x8 pfC[2][2];
            EXPP(st, pfC);
            QK(Kb, 1, st);
            PV(pfC, Vb, 0);
        }
    }

    // drain: last half-stage of tile NT-1
    {
        bf16x8 pfD[2][2];
        EXPP(st, pfD);
        PV(pfD, VgT + (size_t)(NT - 1) * 4096, 1);
    }

    // epilogue
    int plane = (jj * 3 + i) + 6 * kh;
    #pragma unroll
    for (int qi = 0; qi < 2; ++qi) {
        float l = ls2[qi].x + ls2[qi].y;
        l += __shfl_xor(l, 32);
        int row = b * N_DIM + qt * 256 + wave * 64 + qi * 32 + lq;

        if (HALVES == 2) {
            if (h == 0) lsumArr[(size_t)plane * BN + row] = l;
            // O stored unnormalized; reduce divides by (l0+l1)
        } else {
            float inv = 1.0f / l;
            #pragma unroll
            for (int r = 0; r < 16; ++r) { O[0][qi][r] *= inv; O[1][qi][r] *= inv; }
        }

        unsigned short* dst = part + (size_t)plane * PLANE + (size_t)row * 64 + h * 32;
        #pragma unroll
        for (int s = 0; s < 4; ++s) {
            unsigned t00 = pk_rne(O[0][qi][4 * s], O[0][qi][4 * s + 1]);
            unsigned t01 = pk_rne(O[0][qi][4 * s + 2], O[0][qi][4 * s + 3]);
            unsigned t10 = pk_rne(O[1][qi][4 * s], O[1][qi][4 * s + 1]);
            unsigned t11 = pk_rne(O[1][qi][4 * s + 2], O[1][qi][4 * s + 3]);
            u32x2 a = half_swap(t00, t10);
            u32x2 c = half_swap(t01, t11);
            uint4 w; w.x = a.x; w.y = c.x; w.z = a.y; w.w = c.y;
            *(uint4*)&dst[s * 8] = w;
        }
    }
}

// ---------------------------------------------------------------------------
// reduce: HALVES=2: out = (1/3) * sum_pairs (O0+O1)/(l0+l1)
//         HALVES=1: out = (1/3) * sum of 6 normalized bf16 planes
// ---------------------------------------------------------------------------
template<int HALVES>
__global__ __launch_bounds__(256) void reduce_kernel(
    const unsigned short* __restrict__ part, const float* __restrict__ lsumArr,
    float* __restrict__ out)
{
    size_t e = ((size_t)blockIdx.x * 256 + threadIdx.x) * 4;
    int row = (int)(e >> 6);
    float a0 = 0.f, a1 = 0.f, a2 = 0.f, a3 = 0.f;
    #pragma unroll
    for (int pp = 0; pp < 6; ++pp) {
        const unsigned short* p0 = part + (size_t)pp * PLANE + e;
        unsigned u00 = *(const unsigned*)&p0[0];
        unsigned u01 = *(const unsigned*)&p0[2];
        if (HALVES == 2) {
            float l = lsumArr[(size_t)pp * BN + row] + lsumArr[(size_t)(pp + 6) * BN + row];
            float inv = 1.0f / l;
            const unsigned short* p1 = part + (size_t)(pp + 6) * PLANE + e;
            unsigned u10 = *(const unsigned*)&p1[0];
            unsigned u11 = *(const unsigned*)&p1[2];
            a0 += (__builtin_bit_cast(float, u00 << 16) + __builtin_bit_cast(float, u10 << 16)) * inv;
            a1 += (__builtin_bit_cast(float, u00 & 0xffff0000u) + __builtin_bit_cast(float, u10 & 0xffff0000u)) * inv;
            a2 += (__builtin_bit_cast(float, u01 << 16) + __builtin_bit_cast(float, u11 << 16)) * inv;
            a3 += (__builtin_bit_cast(float, u01 & 0xffff0000u) + __builtin_bit_cast(float, u11 & 0xffff0000u)) * inv;
        } else {
            a0 += __builtin_bit_cast(float, u00 << 16);
            a1 += __builtin_bit_cast(float, u00 & 0xffff0000u);
            a2 += __builtin_bit_cast(float, u01 << 16);
            a3 += __builtin_bit_cast(float, u01 & 0xffff0000u);
        }
    }
    f32x4 v;
    v.x = a0 * (1.0f / 3.0f); v.y = a1 * (1.0f / 3.0f);
    v.z = a2 * (1.0f / 3.0f); v.w = a3 * (1.0f / 3.0f);
    *(f32x4*)&out[e] = v;
}

extern "C" void kernel_launch(void* const* d_in, const int* in_sizes, int n_in,
                              void* d_out, int out_size, void* d_ws, size_t ws_size,
                              hipStream_t stream)
{
    const float* x0 = (const float*)d_in[0];
    const float* x1 = (const float*)d_in[1];
    const float* x2 = (const float*)d_in[2];
    const float* w0 = (const float*)d_in[3];
    const float* w1 = (const float*)d_in[4];
    const float* w2 = (const float*)d_in[5];
    float* out = (float*)d_out;

    size_t nElem = (size_t)3 * BN * 64;          // shorts per Q/K/V tensor
    size_t qkvBytes = 3 * nElem * sizeof(unsigned short);
    size_t need2 = qkvBytes + (size_t)12 * PLANE * 2 + (size_t)12 * BN * 4
                 + (size_t)WFRAG_SHORTS * 2;
    bool split = ws_size >= need2;

    unsigned short* Qbf = (unsigned short*)d_ws;
    unsigned short* Kbf = Qbf + nElem;
    unsigned short* Vt  = Kbf + nElem;
    unsigned short* part = Vt + nElem;
    size_t partElems = (size_t)(split ? 12 : 6) * PLANE;
    float* lsumArr = (float*)(part + partElems);
    unsigned short* wfrag = (unsigned short*)(lsumArr + (split ? (size_t)12 * BN : 0));

    hipLaunchKernelGGL(wprep_kernel, dim3(3), dim3(64), 0, stream,
                       w0, w1, w2, wfrag);
    hipLaunchKernelGGL(prep_kernel, dim3(3 * (BN / 128)), dim3(256), 0, stream,
                       x0, x1, x2, wfrag, Qbf, Kbf, Vt);
    if (split) {
        hipLaunchKernelGGL((attn_kernel<2>), dim3(2 * 6 * B_DIM * (N_DIM / 256)), dim3(256), 0, stream,
                           Qbf, Kbf, Vt, part, lsumArr);
        hipLaunchKernelGGL((reduce_kernel<2>), dim3((BN * 64 / 4) / 256), dim3(256), 0, stream,
                           part, lsumArr, out);
    } else {
        hipLaunchKernelGGL((attn_kernel<1>), dim3(6 * B_DIM * (N_DIM / 256)), dim3(256), 0, stream,
                           Qbf, Kbf, Vt, part, lsumArr);
        hipLaunchKernelGGL((reduce_kernel<1>), dim3((BN * 64 / 4) / 256), dim3(256), 0, stream,
                           part, lsumArr, out);
    }
}

// Round 10
// 215.226 us; speedup vs baseline: 6.0481x; 6.0481x over previous
//
#include <hip/hip_runtime.h>
#include <cstdint>
#include <cstddef>

#define B_DIM 16
#define N_DIM 2048
#define BN (B_DIM * N_DIM)          // 32768 rows per modality
#define QSCALE 0.18033688f          // 0.125 * log2(e): P = exp2(S')
#define PLANE ((size_t)BN * 64)     // elems per partial plane
#define MBPLANE ((size_t)N_DIM * 64) // elems per (modality,batch) tensor block
#define WFRAG_K_OFF (3 * 8 * 64 * 8) // shorts: K-frag area offset in wfrag
#define WFRAG_SHORTS (2 * WFRAG_K_OFF)

typedef __attribute__((ext_vector_type(4))) float f32x4;
typedef __attribute__((ext_vector_type(2))) float f32x2;
typedef __attribute__((ext_vector_type(16))) float f32x16;
typedef __attribute__((ext_vector_type(8))) __bf16 bf16x8;
typedef __attribute__((ext_vector_type(2))) unsigned int u32x2;

__device__ __forceinline__ unsigned short f2bf_rne(float f) {
    union { float f; unsigned int u; } v; v.f = f;
    unsigned int u = v.u;
    return (unsigned short)((u + 0x7fffu + ((u >> 16) & 1u)) >> 16);
}
__device__ __forceinline__ unsigned pk_rne(float a, float b) {
    return (unsigned)f2bf_rne(a) | ((unsigned)f2bf_rne(b) << 16);
}
// half_swap(a,b): res.x = {a.lo32, b.lo32}, res.y = {a.hi32, b.hi32}
__device__ __forceinline__ u32x2 half_swap(unsigned a, unsigned b) {
#if __has_builtin(__builtin_amdgcn_permlane32_swap)
    return __builtin_amdgcn_permlane32_swap(a, b, false, false);
#else
    unsigned pa = (unsigned)__shfl_xor((int)a, 32);
    unsigned pb = (unsigned)__shfl_xor((int)b, 32);
    bool hi = (threadIdx.x & 32) != 0;
    u32x2 r;
    r.x = hi ? pb : a;
    r.y = hi ? b : pa;
    return r;
#endif
}

// ---------------------------------------------------------------------------
// wprep: per-lane W fragments (wq scaled, wk) computed ONCE per modality.
// ---------------------------------------------------------------------------
__global__ __launch_bounds__(64) void wprep_kernel(
    const float* __restrict__ w0, const float* __restrict__ w1, const float* __restrict__ w2,
    unsigned short* __restrict__ wfrag)
{
    int m = blockIdx.x;
    const float* W = (m == 0) ? w0 : (m == 1) ? w1 : w2;
    int lane = threadIdx.x;
    int lq = lane & 31, h = lane >> 5;

    #pragma unroll
    for (int mf = 0; mf < 2; ++mf)
        #pragma unroll
        for (int kc = 0; kc < 4; ++kc) {
            int e  = mf * 32 + lq;
            int d0 = kc * 16 + h * 8;
            unsigned uq[4], uk[4];
            #pragma unroll
            for (int t = 0; t < 4; ++t) {
                int d = d0 + 2 * t;
                uq[t] = pk_rne(W[d * 64 + e] * QSCALE, W[(d + 1) * 64 + e] * QSCALE);
                uk[t] = pk_rne(W[e * 64 + d], W[e * 64 + d + 1]);
            }
            unsigned short* dq = wfrag + ((size_t)((m * 8 + kc * 2 + mf) * 64 + lane)) * 8;
            uint4 a; a.x = uq[0]; a.y = uq[1]; a.z = uq[2]; a.w = uq[3];
            uint4 b; b.x = uk[0]; b.y = uk[1]; b.z = uk[2]; b.w = uk[3];
            *(uint4*)dq = a;
            *(uint4*)(dq + WFRAG_K_OFF) = b;
        }
}

// ---------------------------------------------------------------------------
// prep (MFMA): Q = (x@W)*QSCALE, K = x@W^T, V = x^T — tiled slab layouts:
//   Q: [m][b][g=q/64][qi][chunk 0..7][lq][8elem]
//   K: [m][b][kt=key/64][chunk 0..7][key&63][8elem]   (kt stride 4096 shorts)
//   V: [m][b][kt][keygrp 0..7][d 0..63][8 keys]       (kt stride 4096 shorts)
// ---------------------------------------------------------------------------
__global__ __launch_bounds__(256) void prep_kernel(
    const float* __restrict__ x0, const float* __restrict__ x1, const float* __restrict__ x2,
    const unsigned short* __restrict__ wfrag,
    unsigned short* __restrict__ Qbf, unsigned short* __restrict__ Kbf,
    unsigned short* __restrict__ Vt)
{
    __shared__ float xs[128 * 68];

    int m    = blockIdx.x >> 8;
    int tile = blockIdx.x & 255;
    int row0 = tile * 128;
    int b    = row0 >> 11;
    int n0   = row0 & 2047;
    const float* x = (m == 0) ? x0 : (m == 1) ? x1 : x2;
    int tid = threadIdx.x;

    #pragma unroll
    for (int v = 0; v < 8; ++v) {
        int i4 = v * 256 + tid;
        int r = i4 >> 4, c = (i4 & 15) * 4;
        *(f32x4*)&xs[r * 68 + c] = *(const f32x4*)&x[(size_t)row0 * 64 + i4 * 4];
    }
    __syncthreads();

    int lane = tid & 63, wave = tid >> 6, lq = lane & 31, h = lane >> 5;

    bf16x8 wq[2][4], wk[2][4];
    #pragma unroll
    for (int mf = 0; mf < 2; ++mf)
        #pragma unroll
        for (int kc = 0; kc < 4; ++kc) {
            const unsigned short* fq = wfrag + ((size_t)((m * 8 + kc * 2 + mf) * 64 + lane)) * 8;
            wq[mf][kc] = __builtin_bit_cast(bf16x8, *(const uint4*)fq);
            wk[mf][kc] = __builtin_bit_cast(bf16x8, *(const uint4*)(fq + WFRAG_K_OFF));
        }

    bf16x8 xb[4];
    #pragma unroll
    for (int kc = 0; kc < 4; ++kc) {
        const float* xr = &xs[(wave * 32 + lq) * 68 + kc * 16 + h * 8];
        unsigned u[4];
        #pragma unroll
        for (int t = 0; t < 4; ++t) u[t] = pk_rne(xr[2 * t], xr[2 * t + 1]);
        uint4 ua; ua.x = u[0]; ua.y = u[1]; ua.z = u[2]; ua.w = u[3];
        xb[kc] = __builtin_bit_cast(bf16x8, ua);
    }

    f32x16 Qt[2], Kt[2];
    #pragma unroll
    for (int r = 0; r < 16; ++r) { Qt[0][r] = 0.f; Qt[1][r] = 0.f; Kt[0][r] = 0.f; Kt[1][r] = 0.f; }
    #pragma unroll
    for (int kc = 0; kc < 4; ++kc) {
        #pragma unroll
        for (int mf = 0; mf < 2; ++mf) {
            Qt[mf] = __builtin_amdgcn_mfma_f32_32x32x16_bf16(wq[mf][kc], xb[kc], Qt[mf], 0, 0, 0);
            Kt[mf] = __builtin_amdgcn_mfma_f32_32x32x16_bf16(wk[mf][kc], xb[kc], Kt[mf], 0, 0, 0);
        }
    }

    size_t mbBase = ((size_t)m * B_DIM + b) * MBPLANE;
    int nn  = n0 + wave * 32 + lq;
    int g   = nn >> 6;
    int qi  = (nn >> 5) & 1;
    int ktp = nn >> 6, keyp = nn & 63;
    unsigned short* qb = Qbf + mbBase + (size_t)(g * 2 + qi) * 2048 + lq * 8;
    unsigned short* kb = Kbf + mbBase + (size_t)ktp * 4096 + keyp * 8;

    #pragma unroll
    for (int s = 0; s < 4; ++s) {
        int c = 4 * h + s;
        unsigned q00 = pk_rne(Qt[0][4 * s], Qt[0][4 * s + 1]);
        unsigned q01 = pk_rne(Qt[0][4 * s + 2], Qt[0][4 * s + 3]);
        unsigned q10 = pk_rne(Qt[1][4 * s], Qt[1][4 * s + 1]);
        unsigned q11 = pk_rne(Qt[1][4 * s + 2], Qt[1][4 * s + 3]);
        u32x2 a = half_swap(q00, q10);
        u32x2 cc = half_swap(q01, q11);
        uint4 w; w.x = a.x; w.y = cc.x; w.z = a.y; w.w = cc.y;
        *(uint4*)&qb[c * 256] = w;

        unsigned k00 = pk_rne(Kt[0][4 * s], Kt[0][4 * s + 1]);
        unsigned k01 = pk_rne(Kt[0][4 * s + 2], Kt[0][4 * s + 3]);
        unsigned k10 = pk_rne(Kt[1][4 * s], Kt[1][4 * s + 1]);
        unsigned k11 = pk_rne(Kt[1][4 * s + 2], Kt[1][4 * s + 3]);
        u32x2 a2 = half_swap(k00, k10);
        u32x2 c2 = half_swap(k01, k11);
        uint4 w2; w2.x = a2.x; w2.y = c2.x; w2.z = a2.y; w2.w = c2.y;
        *(uint4*)&kb[c * 512] = w2;
    }

    int d  = tid & 63;
    int ng = tid >> 6;
    #pragma unroll
    for (int s = 0; s < 4; ++s) {
        int keystart = n0 + ng * 32 + 8 * s;
        int ktv = keystart >> 6;
        int cv  = (keystart & 63) >> 3;
        uint4 w;
        int rb = ng * 32 + 8 * s;
        w.x = pk_rne(xs[(rb + 0) * 68 + d], xs[(rb + 1) * 68 + d]);
        w.y = pk_rne(xs[(rb + 2) * 68 + d], xs[(rb + 3) * 68 + d]);
        w.z = pk_rne(xs[(rb + 4) * 68 + d], xs[(rb + 5) * 68 + d]);
        w.w = pk_rne(xs[(rb + 6) * 68 + d], xs[(rb + 7) * 68 + d]);
        *(uint4*)&Vt[mbBase + (size_t)(ktv * 8 + cv) * 512 + d * 8] = w;
    }
}

// ---------------------------------------------------------------------------
// attention R10: R7 configuration (grid 768, 64q/wave, XCD swizzle,
// launch_bounds(256,3) — the bound PROVEN spill-free for this state) with
// the LDS staging, DMA, and ALL barriers deleted: K/V fragments are read
// directly from global. After the XCD swizzle the (pair,b) K/V panels are
// L2-resident (R7: FETCH 27 MB), and the fragment reads are the identical
// 16B/lane coalesced pattern the LDS held. Isolates the per-tile
// barrier-convoy + staging cost at CONSTANT occupancy.
// NOTE: (256,5)/(256,4) bounds spill this kernel's ~148-reg state (R4/R9).
// ---------------------------------------------------------------------------
__global__ __launch_bounds__(256, 3) void attn_kernel(
    const unsigned short* __restrict__ Qbf,
    const unsigned short* __restrict__ Kbf,
    const unsigned short* __restrict__ Vt,
    unsigned short* __restrict__ part)
{
    int bid = blockIdx.x;                    // 768 = 8cx * 8qt * 12gh
    int cx  = bid & 7;
    int qt  = (bid >> 3) & 7;
    int gh  = bid >> 6;
    int G   = gh * 8 + cx;                   // [0,96) = p*16 + b
    int p   = G >> 4, b = G & 15;
    int i   = p >> 1, jj = p & 1;
    int j   = i + 1 + jj; if (j >= 3) j -= 3;

    int tid = threadIdx.x, wave = tid >> 6, lane = tid & 63;
    int lq = lane & 31, h = lane >> 5;

    const unsigned short* KgT = Kbf + ((size_t)j * B_DIM + b) * MBPLANE;
    const unsigned short* VgT = Vt  + ((size_t)j * B_DIM + b) * MBPLANE;
    const unsigned short* QgT = Qbf + ((size_t)i * B_DIM + b) * MBPLANE;

    // Q B-frags: wave owns 64 queries (q = qt*256 + wave*64 + qi*32 + lq)
    int g0 = qt * 4 + wave;
    bf16x8 qf[2][4];
    #pragma unroll
    for (int qi = 0; qi < 2; ++qi)
        #pragma unroll
        for (int kc = 0; kc < 4; ++kc)
            qf[qi][kc] = __builtin_bit_cast(bf16x8, *(const uint4*)&QgT[
                (size_t)(g0 * 2 + qi) * 2048 + (kc * 2 + h) * 256 + lq * 8]);

    f32x16 ZERO;
    #pragma unroll
    for (int r = 0; r < 16; ++r) ZERO[r] = 0.f;

    f32x16 O[2][2];                          // [df][qi]
    #pragma unroll
    for (int r = 0; r < 16; ++r) { O[0][0][r] = 0.f; O[0][1][r] = 0.f; O[1][0][r] = 0.f; O[1][1][r] = 0.f; }
    f32x2 ls2[2]; ls2[0] = (f32x2)(0.f); ls2[1] = (f32x2)(0.f);

    // QK of one 32-key half-stage; K fragments straight from L2 (coalesced 1KB/instr)
    auto QK = [&](const unsigned short* Kb, int kf, f32x16 stv[2]) {
        bf16x8 kfr[4];
        #pragma unroll
        for (int kc = 0; kc < 4; ++kc)
            kfr[kc] = __builtin_bit_cast(bf16x8,
                *(const uint4*)&Kb[(2 * kc + h) * 512 + (kf * 32 + lq) * 8]);
        stv[0] = __builtin_amdgcn_mfma_f32_32x32x16_bf16(kfr[0], qf[0][0], ZERO, 0, 0, 0);
        stv[1] = __builtin_amdgcn_mfma_f32_32x32x16_bf16(kfr[0], qf[1][0], ZERO, 0, 0, 0);
        #pragma unroll
        for (int kc = 1; kc < 4; ++kc) {
            stv[0] = __builtin_amdgcn_mfma_f32_32x32x16_bf16(kfr[kc], qf[0][kc], stv[0], 0, 0, 0);
            stv[1] = __builtin_amdgcn_mfma_f32_32x32x16_bf16(kfr[kc], qf[1][kc], stv[1], 0, 0, 0);
        }
    };

    auto EXPP = [&](const f32x16 stv[2], bf16x8 pf[2][2]) {
        #pragma unroll
        for (int qi = 0; qi < 2; ++qi) {
            unsigned pkk[4][2];
            #pragma unroll
            for (int s = 0; s < 4; ++s) {
                float e0 = __builtin_amdgcn_exp2f(stv[qi][4 * s + 0]);
                float e1 = __builtin_amdgcn_exp2f(stv[qi][4 * s + 1]);
                float e2 = __builtin_amdgcn_exp2f(stv[qi][4 * s + 2]);
                float e3 = __builtin_amdgcn_exp2f(stv[qi][4 * s + 3]);
                f32x2 p01; p01.x = e0; p01.y = e1;
                f32x2 p23; p23.x = e2; p23.y = e3;
                ls2[qi] += p01;              // v_pk_add_f32
                ls2[qi] += p23;
                pkk[s][0] = __builtin_amdgcn_perm(
                    __builtin_bit_cast(unsigned, e1), __builtin_bit_cast(unsigned, e0), 0x07060302u);
                pkk[s][1] = __builtin_amdgcn_perm(
                    __builtin_bit_cast(unsigned, e3), __builtin_bit_cast(unsigned, e2), 0x07060302u);
            }
            #pragma unroll
            for (int c = 0; c < 2; ++c) {
                u32x2 rr0 = half_swap(pkk[2 * c][0], pkk[2 * c + 1][0]);
                u32x2 rr1 = half_swap(pkk[2 * c][1], pkk[2 * c + 1][1]);
                uint4 t; t.x = rr0.x; t.y = rr1.x; t.z = rr0.y; t.w = rr1.y;
                pf[qi][c] = __builtin_bit_cast(bf16x8, t);
            }
        }
    };

    // PV of one half-stage; V fragments straight from L2
    auto PV = [&](const bf16x8 pf[2][2], const unsigned short* Vb, int kfp) {
        #pragma unroll
        for (int c = 0; c < 2; ++c) {
            int kcpv = 2 * kfp + c;
            bf16x8 vfr0 = __builtin_bit_cast(bf16x8,
                *(const uint4*)&Vb[(2 * kcpv + h) * 512 + lq * 8]);
            bf16x8 vfr1 = __builtin_bit_cast(bf16x8,
                *(const uint4*)&Vb[(2 * kcpv + h) * 512 + (32 + lq) * 8]);
            O[0][0] = __builtin_amdgcn_mfma_f32_32x32x16_bf16(vfr0, pf[0][c], O[0][0], 0, 0, 0);
            O[0][1] = __builtin_amdgcn_mfma_f32_32x32x16_bf16(vfr0, pf[1][c], O[0][1], 0, 0, 0);
            O[1][0] = __builtin_amdgcn_mfma_f32_32x32x16_bf16(vfr1, pf[0][c], O[1][0], 0, 0, 0);
            O[1][1] = __builtin_amdgcn_mfma_f32_32x32x16_bf16(vfr1, pf[1][c], O[1][1], 0, 0, 0);
        }
    };

    // pipelined loop (no barriers): exp/PV of previous half-stage between QKs
    f32x16 st[2];
    QK(KgT, 0, st);
    {
        bf16x8 pfA[2][2];
        EXPP(st, pfA);
        QK(KgT, 1, st);
        PV(pfA, VgT, 0);
    }

    for (int lt = 1; lt < 32; ++lt) {
        const unsigned short* Kb = KgT + (size_t)lt * 4096;
        const unsigned short* Vb = VgT + (size_t)lt * 4096;
        {
            bf16x8 pfB[2][2];
            EXPP(st, pfB);
            PV(pfB, Vb - 4096, 1);           // finish tile lt-1
        }
        QK(Kb, 0, st);
        {
            bf16x8 pfC[2][2];
            EXPP(st, pfC);
            QK(Kb, 1, st);
            PV(pfC, Vb, 0);
        }
    }

    // drain: last half-stage of tile 31
    {
        bf16x8 pfD[2][2];
        EXPP(st, pfD);
        PV(pfD, VgT + (size_t)31 * 4096, 1);
    }

    // epilogue: normalize, half-swap to row layout, store bf16 partial rows
    int plane = jj * 3 + i;
    #pragma unroll
    for (int qi = 0; qi < 2; ++qi) {
        float l = ls2[qi].x + ls2[qi].y;
        l += __shfl_xor(l, 32);
        float inv = 1.0f / l;
        #pragma unroll
        for (int r = 0; r < 16; ++r) { O[0][qi][r] *= inv; O[1][qi][r] *= inv; }

        int row = b * N_DIM + qt * 256 + wave * 64 + qi * 32 + lq;
        unsigned short* dst = part + (size_t)plane * PLANE + (size_t)row * 64 + h * 32;
        #pragma unroll
        for (int s = 0; s < 4; ++s) {
            unsigned t00 = pk_rne(O[0][qi][4 * s], O[0][qi][4 * s + 1]);
            unsigned t01 = pk_rne(O[0][qi][4 * s + 2], O[0][qi][4 * s + 3]);
            unsigned t10 = pk_rne(O[1][qi][4 * s], O[1][qi][4 * s + 1]);
            unsigned t11 = pk_rne(O[1][qi][4 * s + 2], O[1][qi][4 * s + 3]);
            u32x2 a = half_swap(t00, t10);
            u32x2 c = half_swap(t01, t11);
            uint4 w; w.x = a.x; w.y = c.x; w.z = a.y; w.w = c.y;
            *(uint4*)&dst[s * 8] = w;
        }
    }
}

// ---------------------------------------------------------------------------
// reduce: out = (1/3) * sum of 6 normalized bf16 planes
// ---------------------------------------------------------------------------
__global__ __launch_bounds__(256) void reduce_kernel(
    const unsigned short* __restrict__ part, float* __restrict__ out)
{
    size_t e = ((size_t)blockIdx.x * 256 + threadIdx.x) * 4;
    float a0 = 0.f, a1 = 0.f, a2 = 0.f, a3 = 0.f;
    #pragma unroll
    for (int q = 0; q < 6; ++q) {
        const unsigned short* pp = part + (size_t)q * PLANE + e;
        unsigned u0 = *(const unsigned*)&pp[0];
        unsigned u1 = *(const unsigned*)&pp[2];
        a0 += __builtin_bit_cast(float, u0 << 16);
        a1 += __builtin_bit_cast(float, u0 & 0xffff0000u);
        a2 += __builtin_bit_cast(float, u1 << 16);
        a3 += __builtin_bit_cast(float, u1 & 0xffff0000u);
    }
    f32x4 v;
    v.x = a0 * (1.0f / 3.0f); v.y = a1 * (1.0f / 3.0f);
    v.z = a2 * (1.0f / 3.0f); v.w = a3 * (1.0f / 3.0f);
    *(f32x4*)&out[e] = v;
}

extern "C" void kernel_launch(void* const* d_in, const int* in_sizes, int n_in,
                              void* d_out, int out_size, void* d_ws, size_t ws_size,
                              hipStream_t stream)
{
    const float* x0 = (const float*)d_in[0];
    const float* x1 = (const float*)d_in[1];
    const float* x2 = (const float*)d_in[2];
    const float* w0 = (const float*)d_in[3];
    const float* w1 = (const float*)d_in[4];
    const float* w2 = (const float*)d_in[5];
    float* out = (float*)d_out;

    size_t nElem = (size_t)3 * BN * 64;
    unsigned short* Qbf = (unsigned short*)d_ws;
    unsigned short* Kbf = Qbf + nElem;
    unsigned short* Vt  = Kbf + nElem;
    unsigned short* part = Vt + nElem;            // 6 planes * BN*64 bf16
    unsigned short* wfrag = part + 6 * PLANE;     // 48 KB of W fragments

    hipLaunchKernelGGL(wprep_kernel, dim3(3), dim3(64), 0, stream,
                       w0, w1, w2, wfrag);
    hipLaunchKernelGGL(prep_kernel, dim3(3 * (BN / 128)), dim3(256), 0, stream,
                       x0, x1, x2, wfrag, Qbf, Kbf, Vt);
    hipLaunchKernelGGL(attn_kernel, dim3(6 * B_DIM * (N_DIM / 256)), dim3(256), 0, stream,
                       Qbf, Kbf, Vt, part);
    hipLaunchKernelGGL(reduce_kernel, dim3((BN * 64 / 4) / 256), dim3(256), 0, stream,
                       part, out);
}

// Round 11
// 197.637 us; speedup vs baseline: 6.5863x; 1.0890x over previous
//
#include <hip/hip_runtime.h>
#include <cstdint>
#include <cstddef>

#define B_DIM 16
#define N_DIM 2048
#define BN (B_DIM * N_DIM)          // 32768 rows per modality
#define QSCALE 0.18033688f          // 0.125 * log2(e): P = exp2(S')
#define PLANE ((size_t)BN * 64)     // elems per (jj,i) partial plane
#define MBPLANE ((size_t)N_DIM * 64) // elems per (modality,batch) tensor block
#define WFRAG_K_OFF (3 * 8 * 64 * 8) // shorts: K-frag area offset in wfrag

typedef __attribute__((ext_vector_type(4))) float f32x4;
typedef __attribute__((ext_vector_type(2))) float f32x2;
typedef __attribute__((ext_vector_type(16))) float f32x16;
typedef __attribute__((ext_vector_type(8))) __bf16 bf16x8;
typedef __attribute__((ext_vector_type(2))) unsigned int u32x2;

__device__ __forceinline__ unsigned short f2bf_rne(float f) {
    union { float f; unsigned int u; } v; v.f = f;
    unsigned int u = v.u;
    return (unsigned short)((u + 0x7fffu + ((u >> 16) & 1u)) >> 16);
}
__device__ __forceinline__ unsigned pk_rne(float a, float b) {
    return (unsigned)f2bf_rne(a) | ((unsigned)f2bf_rne(b) << 16);
}
// half_swap(a,b): res.x = {a.lo32, b.lo32}, res.y = {a.hi32, b.hi32}
__device__ __forceinline__ u32x2 half_swap(unsigned a, unsigned b) {
#if __has_builtin(__builtin_amdgcn_permlane32_swap)
    return __builtin_amdgcn_permlane32_swap(a, b, false, false);
#else
    unsigned pa = (unsigned)__shfl_xor((int)a, 32);
    unsigned pb = (unsigned)__shfl_xor((int)b, 32);
    bool hi = (threadIdx.x & 32) != 0;
    u32x2 r;
    r.x = hi ? pb : a;
    r.y = hi ? b : pa;
    return r;
#endif
}

// async global->LDS, 16B per lane; LDS dest = wave-uniform base + lane*16
__device__ __forceinline__ void g2lds16(const unsigned short* g, unsigned short* ldsbase) {
#if __has_builtin(__builtin_amdgcn_global_load_lds)
    __builtin_amdgcn_global_load_lds(
        (const __attribute__((address_space(1))) unsigned int*)g,
        (__attribute__((address_space(3))) unsigned int*)ldsbase,
        16, 0, 0);
#else
    int ln = threadIdx.x & 63;
    *(uint4*)(ldsbase + ln * 8) = *(const uint4*)g;
#endif
}

// ---------------------------------------------------------------------------
// wprep: per-lane W fragments (wq scaled, wk) computed ONCE per modality.
// ---------------------------------------------------------------------------
__global__ __launch_bounds__(64) void wprep_kernel(
    const float* __restrict__ w0, const float* __restrict__ w1, const float* __restrict__ w2,
    unsigned short* __restrict__ wfrag)
{
    int m = blockIdx.x;
    const float* W = (m == 0) ? w0 : (m == 1) ? w1 : w2;
    int lane = threadIdx.x;
    int lq = lane & 31, h = lane >> 5;

    #pragma unroll
    for (int mf = 0; mf < 2; ++mf)
        #pragma unroll
        for (int kc = 0; kc < 4; ++kc) {
            int e  = mf * 32 + lq;
            int d0 = kc * 16 + h * 8;
            unsigned uq[4], uk[4];
            #pragma unroll
            for (int t = 0; t < 4; ++t) {
                int d = d0 + 2 * t;
                uq[t] = pk_rne(W[d * 64 + e] * QSCALE, W[(d + 1) * 64 + e] * QSCALE);
                uk[t] = pk_rne(W[e * 64 + d], W[e * 64 + d + 1]);
            }
            unsigned short* dq = wfrag + ((size_t)((m * 8 + kc * 2 + mf) * 64 + lane)) * 8;
            uint4 a; a.x = uq[0]; a.y = uq[1]; a.z = uq[2]; a.w = uq[3];
            uint4 b; b.x = uk[0]; b.y = uk[1]; b.z = uk[2]; b.w = uk[3];
            *(uint4*)dq = a;
            *(uint4*)(dq + WFRAG_K_OFF) = b;
        }
}

// ---------------------------------------------------------------------------
// prep (MFMA): Q = (x@W)*QSCALE, K = x@W^T, V = x^T — tiled slab layouts:
//   Q: [m][b][g=q/64][qi][chunk 0..7][lq][8elem]
//   K: [m][b][kt=key/64][chunk 0..7][key&63][8elem]
//   V: [m][b][kt][keygrp 0..7][d 0..63][8 keys]
// W fragments loaded from wprep output (16 coalesced uint4/thread).
// ---------------------------------------------------------------------------
__global__ __launch_bounds__(256) void prep_kernel(
    const float* __restrict__ x0, const float* __restrict__ x1, const float* __restrict__ x2,
    const unsigned short* __restrict__ wfrag,
    unsigned short* __restrict__ Qbf, unsigned short* __restrict__ Kbf,
    unsigned short* __restrict__ Vt)
{
    __shared__ float xs[128 * 68];

    int m    = blockIdx.x >> 8;
    int tile = blockIdx.x & 255;
    int row0 = tile * 128;
    int b    = row0 >> 11;
    int n0   = row0 & 2047;
    const float* x = (m == 0) ? x0 : (m == 1) ? x1 : x2;
    int tid = threadIdx.x;

    #pragma unroll
    for (int v = 0; v < 8; ++v) {
        int i4 = v * 256 + tid;
        int r = i4 >> 4, c = (i4 & 15) * 4;
        *(f32x4*)&xs[r * 68 + c] = *(const f32x4*)&x[(size_t)row0 * 64 + i4 * 4];
    }
    __syncthreads();

    int lane = tid & 63, wave = tid >> 6, lq = lane & 31, h = lane >> 5;

    bf16x8 wq[2][4], wk[2][4];
    #pragma unroll
    for (int mf = 0; mf < 2; ++mf)
        #pragma unroll
        for (int kc = 0; kc < 4; ++kc) {
            const unsigned short* fq = wfrag + ((size_t)((m * 8 + kc * 2 + mf) * 64 + lane)) * 8;
            wq[mf][kc] = __builtin_bit_cast(bf16x8, *(const uint4*)fq);
            wk[mf][kc] = __builtin_bit_cast(bf16x8, *(const uint4*)(fq + WFRAG_K_OFF));
        }

    bf16x8 xb[4];
    #pragma unroll
    for (int kc = 0; kc < 4; ++kc) {
        const float* xr = &xs[(wave * 32 + lq) * 68 + kc * 16 + h * 8];
        unsigned u[4];
        #pragma unroll
        for (int t = 0; t < 4; ++t) u[t] = pk_rne(xr[2 * t], xr[2 * t + 1]);
        uint4 ua; ua.x = u[0]; ua.y = u[1]; ua.z = u[2]; ua.w = u[3];
        xb[kc] = __builtin_bit_cast(bf16x8, ua);
    }

    f32x16 Qt[2], Kt[2];
    #pragma unroll
    for (int r = 0; r < 16; ++r) { Qt[0][r] = 0.f; Qt[1][r] = 0.f; Kt[0][r] = 0.f; Kt[1][r] = 0.f; }
    #pragma unroll
    for (int kc = 0; kc < 4; ++kc) {
        #pragma unroll
        for (int mf = 0; mf < 2; ++mf) {
            Qt[mf] = __builtin_amdgcn_mfma_f32_32x32x16_bf16(wq[mf][kc], xb[kc], Qt[mf], 0, 0, 0);
            Kt[mf] = __builtin_amdgcn_mfma_f32_32x32x16_bf16(wk[mf][kc], xb[kc], Kt[mf], 0, 0, 0);
        }
    }

    size_t mbBase = ((size_t)m * B_DIM + b) * MBPLANE;
    int nn  = n0 + wave * 32 + lq;
    int g   = nn >> 6;
    int qi  = (nn >> 5) & 1;
    int ktp = nn >> 6, keyp = nn & 63;
    unsigned short* qb = Qbf + mbBase + (size_t)(g * 2 + qi) * 2048 + lq * 8;
    unsigned short* kb = Kbf + mbBase + (size_t)ktp * 4096 + keyp * 8;

    #pragma unroll
    for (int s = 0; s < 4; ++s) {
        int c = 4 * h + s;
        unsigned q00 = pk_rne(Qt[0][4 * s], Qt[0][4 * s + 1]);
        unsigned q01 = pk_rne(Qt[0][4 * s + 2], Qt[0][4 * s + 3]);
        unsigned q10 = pk_rne(Qt[1][4 * s], Qt[1][4 * s + 1]);
        unsigned q11 = pk_rne(Qt[1][4 * s + 2], Qt[1][4 * s + 3]);
        u32x2 a = half_swap(q00, q10);
        u32x2 cc = half_swap(q01, q11);
        uint4 w; w.x = a.x; w.y = cc.x; w.z = a.y; w.w = cc.y;
        *(uint4*)&qb[c * 256] = w;

        unsigned k00 = pk_rne(Kt[0][4 * s], Kt[0][4 * s + 1]);
        unsigned k01 = pk_rne(Kt[0][4 * s + 2], Kt[0][4 * s + 3]);
        unsigned k10 = pk_rne(Kt[1][4 * s], Kt[1][4 * s + 1]);
        unsigned k11 = pk_rne(Kt[1][4 * s + 2], Kt[1][4 * s + 3]);
        u32x2 a2 = half_swap(k00, k10);
        u32x2 c2 = half_swap(k01, k11);
        uint4 w2; w2.x = a2.x; w2.y = c2.x; w2.z = a2.y; w2.w = c2.y;
        *(uint4*)&kb[c * 512] = w2;
    }

    int d  = tid & 63;
    int ng = tid >> 6;
    #pragma unroll
    for (int s = 0; s < 4; ++s) {
        int keystart = n0 + ng * 32 + 8 * s;
        int ktv = keystart >> 6;
        int cv  = (keystart & 63) >> 3;
        uint4 w;
        int rb = ng * 32 + 8 * s;
        w.x = pk_rne(xs[(rb + 0) * 68 + d], xs[(rb + 1) * 68 + d]);
        w.y = pk_rne(xs[(rb + 2) * 68 + d], xs[(rb + 3) * 68 + d]);
        w.z = pk_rne(xs[(rb + 4) * 68 + d], xs[(rb + 5) * 68 + d]);
        w.w = pk_rne(xs[(rb + 6) * 68 + d], xs[(rb + 7) * 68 + d]);
        *(uint4*)&Vt[mbBase + (size_t)(ktv * 8 + cv) * 512 + d * 8] = w;
    }
}

// ---------------------------------------------------------------------------
// attention (R7 final): 64q/wave, double-buffered 64-key tiles (32 KB LDS),
// PV-before-barrier ordering, XCD-aware swizzle (bid = cx + 8*qt + 64*gh;
// all 48 blocks of batch b land on XCD b&7 -> K/V panels L2-resident,
// FETCH 27 MB). launch_bounds(256,3): the ~148-reg/wave state (O 64 acc +
// st 32 + qf 32 + transients, unified VGPR/AGPR file) spills at any
// tighter bound (R4/R9: WRITE exploded to GBs). Measured: attn 115.7 us,
// latency-bound plateau — schedule variants, occupancy levers, instruction
// cuts, and no-LDS all measured neutral-or-worse (R0-R10).
// ---------------------------------------------------------------------------
__global__ __launch_bounds__(256, 3) void attn_kernel(
    const unsigned short* __restrict__ Qbf,
    const unsigned short* __restrict__ Kbf,
    const unsigned short* __restrict__ Vt,
    unsigned short* __restrict__ part)
{
    __shared__ unsigned short Ks[2][4096];   // 8 slabs x [key 0..63][8elem]
    __shared__ unsigned short Vs[2][4096];   // 8 slabs x [d 0..63][8 keys]

    int bid = blockIdx.x;                    // 768 = 6 pairs * 16 b * 8 qt
    int cx  = bid & 7;
    int qt  = (bid >> 3) & 7;
    int gh  = bid >> 6;                      // [0,12)
    int G   = gh * 8 + cx;                   // [0,96) = p*16 + b
    int p   = G >> 4;
    int b   = G & 15;
    int i   = p >> 1, jj = p & 1;
    int j   = i + 1 + jj; if (j >= 3) j -= 3;

    int tid = threadIdx.x, wave = tid >> 6, lane = tid & 63;
    int lq = lane & 31, h = lane >> 5;

    const unsigned short* KgT = Kbf + ((size_t)j * B_DIM + b) * MBPLANE;
    const unsigned short* VgT = Vt  + ((size_t)j * B_DIM + b) * MBPLANE;
    const unsigned short* QgT = Qbf + ((size_t)i * B_DIM + b) * MBPLANE;

    // wave stages slabs {2w, 2w+1} of K and V; global side contiguous 1KB
    int c0 = wave * 2;
    auto stage = [&](int buf, int kt) {
        const unsigned short* gk = KgT + ((size_t)(kt * 8 + c0) * 64 + lane) * 8;
        const unsigned short* gv = VgT + ((size_t)(kt * 8 + c0) * 64 + lane) * 8;
        g2lds16(gk,       &Ks[buf][c0 * 512]);
        g2lds16(gk + 512, &Ks[buf][c0 * 512 + 512]);
        g2lds16(gv,       &Vs[buf][c0 * 512]);
        g2lds16(gv + 512, &Vs[buf][c0 * 512 + 512]);
    };

    // prologue: stage tiles 0 and 1
    stage(0, 0);
    stage(1, 1);

    // Q B-frags: wave owns 64 queries (q = qt*256 + wave*64 + qi*32 + lq)
    int g0 = qt * 4 + wave;
    bf16x8 qf[2][4];
    #pragma unroll
    for (int qi = 0; qi < 2; ++qi)
        #pragma unroll
        for (int kc = 0; kc < 4; ++kc)
            qf[qi][kc] = __builtin_bit_cast(bf16x8, *(const uint4*)&QgT[
                (size_t)(g0 * 2 + qi) * 2048 + (kc * 2 + h) * 256 + lq * 8]);

    // loop-invariant zero accumulator (C-operand; avoids per-stage v_movs)
    f32x16 ZERO;
    #pragma unroll
    for (int r = 0; r < 16; ++r) ZERO[r] = 0.f;

    f32x16 O[2][2];                          // [df][qi]
    #pragma unroll
    for (int r = 0; r < 16; ++r) { O[0][0][r] = 0.f; O[0][1][r] = 0.f; O[1][0][r] = 0.f; O[1][1][r] = 0.f; }
    f32x2 ls2[2]; ls2[0] = (f32x2)(0.f); ls2[1] = (f32x2)(0.f);

    // QK of one 32-key half-stage for both qi; interleaved independent chains
    auto QK = [&](const unsigned short* Kb, int kf, f32x16 stv[2]) {
        bf16x8 kfr[4];
        #pragma unroll
        for (int kc = 0; kc < 4; ++kc)
            kfr[kc] = __builtin_bit_cast(bf16x8,
                *(const uint4*)&Kb[(2 * kc + h) * 512 + (kf * 32 + lq) * 8]);
        stv[0] = __builtin_amdgcn_mfma_f32_32x32x16_bf16(kfr[0], qf[0][0], ZERO, 0, 0, 0);
        stv[1] = __builtin_amdgcn_mfma_f32_32x32x16_bf16(kfr[0], qf[1][0], ZERO, 0, 0, 0);
        #pragma unroll
        for (int kc = 1; kc < 4; ++kc) {
            stv[0] = __builtin_amdgcn_mfma_f32_32x32x16_bf16(kfr[kc], qf[0][kc], stv[0], 0, 0, 0);
            stv[1] = __builtin_amdgcn_mfma_f32_32x32x16_bf16(kfr[kc], qf[1][kc], stv[1], 0, 0, 0);
        }
    };

    // exp2 + lsum + pack scores into P-fragments for both qi
    auto EXPP = [&](const f32x16 stv[2], bf16x8 pf[2][2]) {
        #pragma unroll
        for (int qi = 0; qi < 2; ++qi) {
            unsigned pkk[4][2];
            #pragma unroll
            for (int s = 0; s < 4; ++s) {
                float e0 = __builtin_amdgcn_exp2f(stv[qi][4 * s + 0]);
                float e1 = __builtin_amdgcn_exp2f(stv[qi][4 * s + 1]);
                float e2 = __builtin_amdgcn_exp2f(stv[qi][4 * s + 2]);
                float e3 = __builtin_amdgcn_exp2f(stv[qi][4 * s + 3]);
                f32x2 p01; p01.x = e0; p01.y = e1;
                f32x2 p23; p23.x = e2; p23.y = e3;
                ls2[qi] += p01;              // v_pk_add_f32
                ls2[qi] += p23;
                pkk[s][0] = __builtin_amdgcn_perm(
                    __builtin_bit_cast(unsigned, e1), __builtin_bit_cast(unsigned, e0), 0x07060302u);
                pkk[s][1] = __builtin_amdgcn_perm(
                    __builtin_bit_cast(unsigned, e3), __builtin_bit_cast(unsigned, e2), 0x07060302u);
            }
            #pragma unroll
            for (int c = 0; c < 2; ++c) {
                u32x2 rr0 = half_swap(pkk[2 * c][0], pkk[2 * c + 1][0]);
                u32x2 rr1 = half_swap(pkk[2 * c][1], pkk[2 * c + 1][1]);
                uint4 t; t.x = rr0.x; t.y = rr1.x; t.z = rr0.y; t.w = rr1.y;
                pf[qi][c] = __builtin_bit_cast(bf16x8, t);
            }
        }
    };

    // PV of one half-stage: 4 shared vfr reads feed both qi accumulators
    auto PV = [&](const bf16x8 pf[2][2], const unsigned short* Vb, int kfp) {
        #pragma unroll
        for (int c = 0; c < 2; ++c) {
            int kcpv = 2 * kfp + c;
            bf16x8 vfr0 = __builtin_bit_cast(bf16x8,
                *(const uint4*)&Vb[(2 * kcpv + h) * 512 + lq * 8]);
            bf16x8 vfr1 = __builtin_bit_cast(bf16x8,
                *(const uint4*)&Vb[(2 * kcpv + h) * 512 + (32 + lq) * 8]);
            O[0][0] = __builtin_amdgcn_mfma_f32_32x32x16_bf16(vfr0, pf[0][c], O[0][0], 0, 0, 0);
            O[0][1] = __builtin_amdgcn_mfma_f32_32x32x16_bf16(vfr0, pf[1][c], O[0][1], 0, 0, 0);
            O[1][0] = __builtin_amdgcn_mfma_f32_32x32x16_bf16(vfr1, pf[0][c], O[1][0], 0, 0, 0);
            O[1][1] = __builtin_amdgcn_mfma_f32_32x32x16_bf16(vfr1, pf[1][c], O[1][1], 0, 0, 0);
        }
    };

    __syncthreads();    // publishes tiles 0,1

    // prologue compute: stage 0 (tile 0 kf0) and start of stage 1
    f32x16 st[2];
    QK(Ks[0], 0, st);
    {
        bf16x8 pfA[2][2];
        EXPP(st, pfA);                       // stage 0
        QK(Ks[0], 1, st);                    // stage 1
        PV(pfA, Vs[0], 0);                   // stage 0
    }

    for (int kt = 1; kt < 32; ++kt) {
        {
            bf16x8 pfB[2][2];
            EXPP(st, pfB);                   // stage 2kt-1 (tile kt-1, kf1)
            PV(pfB, Vs[(kt - 1) & 1], 1);    // last read of tile kt-1 V
        }
        __syncthreads();                     // publish tile kt; tile kt-1 bufs free
        if (kt < 31) stage((kt + 1) & 1, kt + 1);
        QK(Ks[kt & 1], 0, st);               // stage 2kt
        {
            bf16x8 pfC[2][2];
            EXPP(st, pfC);                   // stage 2kt
            QK(Ks[kt & 1], 1, st);           // stage 2kt+1
            PV(pfC, Vs[kt & 1], 0);          // stage 2kt
        }
    }

    // drain: stage 63 (tile 31, kf1, buf 1)
    {
        bf16x8 pfD[2][2];
        EXPP(st, pfD);
        PV(pfD, Vs[1], 1);
    }

    // epilogue: normalize, half-swap to row layout, store bf16 partial rows
    #pragma unroll
    for (int qi = 0; qi < 2; ++qi) {
        float l = ls2[qi].x + ls2[qi].y;
        l += __shfl_xor(l, 32);
        float inv = 1.0f / l;
        #pragma unroll
        for (int r = 0; r < 16; ++r) { O[0][qi][r] *= inv; O[1][qi][r] *= inv; }

        unsigned short* dst = part + ((size_t)jj * 3 + i) * PLANE
            + (size_t)(b * N_DIM + qt * 256 + wave * 64 + qi * 32 + lq) * 64 + h * 32;
        #pragma unroll
        for (int s = 0; s < 4; ++s) {
            unsigned t00 = pk_rne(O[0][qi][4 * s], O[0][qi][4 * s + 1]);
            unsigned t01 = pk_rne(O[0][qi][4 * s + 2], O[0][qi][4 * s + 3]);
            unsigned t10 = pk_rne(O[1][qi][4 * s], O[1][qi][4 * s + 1]);
            unsigned t11 = pk_rne(O[1][qi][4 * s + 2], O[1][qi][4 * s + 3]);
            u32x2 a = half_swap(t00, t10);
            u32x2 c = half_swap(t01, t11);
            uint4 w; w.x = a.x; w.y = c.x; w.z = a.y; w.w = c.y;
            *(uint4*)&dst[s * 8] = w;
        }
    }
}

// ---------------------------------------------------------------------------
// reduce: out = (1/3) * sum of 6 bf16 partial planes
// ---------------------------------------------------------------------------
__global__ __launch_bounds__(256) void reduce_kernel(
    const unsigned short* __restrict__ part, float* __restrict__ out)
{
    size_t e = ((size_t)blockIdx.x * 256 + threadIdx.x) * 4;
    float a0 = 0.f, a1 = 0.f, a2 = 0.f, a3 = 0.f;
    #pragma unroll
    for (int q = 0; q < 6; ++q) {
        const unsigned short* pp = part + (size_t)q * PLANE + e;
        unsigned u0 = *(const unsigned*)&pp[0];
        unsigned u1 = *(const unsigned*)&pp[2];
        a0 += __builtin_bit_cast(float, u0 << 16);
        a1 += __builtin_bit_cast(float, u0 & 0xffff0000u);
        a2 += __builtin_bit_cast(float, u1 << 16);
        a3 += __builtin_bit_cast(float, u1 & 0xffff0000u);
    }
    f32x4 v;
    v.x = a0 * (1.0f / 3.0f); v.y = a1 * (1.0f / 3.0f);
    v.z = a2 * (1.0f / 3.0f); v.w = a3 * (1.0f / 3.0f);
    *(f32x4*)&out[e] = v;
}

extern "C" void kernel_launch(void* const* d_in, const int* in_sizes, int n_in,
                              void* d_out, int out_size, void* d_ws, size_t ws_size,
                              hipStream_t stream)
{
    const float* x0 = (const float*)d_in[0];
    const float* x1 = (const float*)d_in[1];
    const float* x2 = (const float*)d_in[2];
    const float* w0 = (const float*)d_in[3];
    const float* w1 = (const float*)d_in[4];
    const float* w2 = (const float*)d_in[5];
    float* out = (float*)d_out;

    size_t nElem = (size_t)3 * BN * 64;
    unsigned short* Qbf = (unsigned short*)d_ws;
    unsigned short* Kbf = Qbf + nElem;
    unsigned short* Vt  = Kbf + nElem;
    unsigned short* part = Vt + nElem;            // 6 planes * BN*64 bf16
    unsigned short* wfrag = part + 6 * PLANE;     // 48 KB of W fragments

    hipLaunchKernelGGL(wprep_kernel, dim3(3), dim3(64), 0, stream,
                       w0, w1, w2, wfrag);
    hipLaunchKernelGGL(prep_kernel, dim3(3 * (BN / 128)), dim3(256), 0, stream,
                       x0, x1, x2, wfrag, Qbf, Kbf, Vt);
    hipLaunchKernelGGL(attn_kernel, dim3(6 * B_DIM * (N_DIM / 256)), dim3(256), 0, stream,
                       Qbf, Kbf, Vt, part);
    hipLaunchKernelGGL(reduce_kernel, dim3((BN * 64 / 4) / 256), dim3(256), 0, stream,
                       part, out);
}